// Round 1
// baseline (1267.591 us; speedup 1.0000x reference)
//
#include <hip/hip_runtime.h>

#define HID 256
#define AS_LD 328   // u16; full-K A-tile row stride (656 B, 16B-aligned rows)
#define TB_LD 264   // u16; epilogue transpose row stride (528 B, 16B-aligned)

typedef unsigned short u16;
typedef unsigned int u32;
typedef short bf16x8 __attribute__((ext_vector_type(8)));
typedef float f32x4 __attribute__((ext_vector_type(4)));
typedef u16 u16x8 __attribute__((ext_vector_type(8)));

static __device__ __forceinline__ float bf2f(u16 b) {
    u32 u = ((u32)b) << 16;
    return __uint_as_float(u);
}
static __device__ __forceinline__ u16 f2bf(float f) {
    u32 u = __float_as_uint(f);
    return (u16)((u + 0x7FFFu + ((u >> 16) & 1u)) >> 16);  // RN-even
}

// ---------------------------------------------------------------------------
// Fused gather + GEMM + relu, tile 64 rows x 256 cols, 512 threads, 8 waves.
// K is staged into LDS ONCE per block (full 320-wide A-tile, 64x328 u16):
//   c1 gather: each dst row's 6 neighbor rows are read as FULL 512-B
//     contiguous bursts (8 lanes x 64 B in one 4-instruction group) -> one
//     DRAM page activation per neighbor row instead of 4 scattered 128-B
//     touches. fp32 register sum -> bf16 -> LDS.
//   c2 chunks: direct rows of Bd (bf16, nt-loaded)
//   c3 chunks: fp32 rows of Cf (K < Kc), converted
// Compute: barrier-free MFMA loop over all K-chunks (B frags JIT, L2-hot).
// Epilogue: 2-pass LDS transpose (32x256) -> full-line nontemporal stores.
// ---------------------------------------------------------------------------
__global__ __launch_bounds__(512, 4) void fused_layer(
    const u16* __restrict__ Sg, const int* __restrict__ graph, int c1,
    const u16* __restrict__ Bd, int ldbd, int c2,
    const float* __restrict__ Cf, int ldcf, int Kc, int c3,
    const u16* __restrict__ WB, int ldw,
    const float* __restrict__ bias,
    u16* __restrict__ C, int M)
{
    __shared__ __align__(16) u16 lds[64 * AS_LD];   // 41,984 B (union: A-tile / transpose)

    const int t    = threadIdx.x;
    const int w    = t >> 6;           // 0..7
    const int lane = t & 63;
    const int row0 = blockIdx.x * 64;
    const int wc   = w * 32;           // wave's 32 columns
    const int fr   = lane & 15;
    const int fq   = lane >> 4;

    const int g  = t & 7;              // granule within row
    const int ra = t >> 3;             // 0..63 -> one A row per thread
    const int gr = row0 + ra;
    u16* Ar = lds + ra * AS_LD;

    // ---- stage the FULL K extent into LDS (one pass, 2 barriers/block) ----
    if (c1 > 0) {
        // assumes c1*64 == 256 (full Sg row); thread sums cols [g*32, g*32+32)
        int nbi[6];
        const int* gp = graph + (size_t)(gr < M ? gr : 0) * 6;
        #pragma unroll
        for (int j = 0; j < 6; ++j) nbi[j] = __builtin_nontemporal_load(&gp[j]);

        const int cb = g * 32;
        float sa[32];
        #pragma unroll
        for (int e = 0; e < 32; ++e) sa[e] = 0.f;

        u16x8 cur[4], nxt[4];
        {
            const u16* p = Sg + (size_t)nbi[0] * 256 + cb;
            #pragma unroll
            for (int q = 0; q < 4; ++q) cur[q] = *(const u16x8*)(p + q * 8);
        }
        #pragma unroll
        for (int j = 0; j < 6; ++j) {
            if (j < 5) {
                const u16* p = Sg + (size_t)nbi[j + 1] * 256 + cb;
                #pragma unroll
                for (int q = 0; q < 4; ++q) nxt[q] = *(const u16x8*)(p + q * 8);
            }
            #pragma unroll
            for (int q = 0; q < 4; ++q)
                #pragma unroll
                for (int e = 0; e < 8; ++e) sa[q * 8 + e] += bf2f(cur[q][e]);
            #pragma unroll
            for (int q = 0; q < 4; ++q) cur[q] = nxt[q];
        }
        #pragma unroll
        for (int q = 0; q < 4; ++q) {
            u16 o[8];
            #pragma unroll
            for (int e = 0; e < 8; ++e) o[e] = f2bf(sa[q * 8 + e]);
            *(uint4*)(Ar + cb + q * 8) = *(const uint4*)o;
        }
    }
    if (c2 > 0) {
        const u16* bdp = Bd + (size_t)(gr < M ? gr : 0) * ldbd;
        for (int c = 0; c < c2; ++c) {
            const u16x8 v = __builtin_nontemporal_load(
                (const u16x8*)(bdp + c * 64 + g * 8));
            *(u16x8*)(Ar + (c1 + c) * 64 + g * 8) = v;
        }
    }
    if (c3 > 0) {
        for (int c = 0; c < c3; ++c) {
            const int kb = c * 64;
            u16 tmp[8];
            #pragma unroll
            for (int i = 0; i < 8; ++i) {
                const int k = kb + g * 8 + i;
                const float v = (gr < M && k < Kc) ? Cf[(size_t)gr * ldcf + k] : 0.f;
                tmp[i] = f2bf(v);
            }
            *(uint4*)(Ar + (c1 + c2 + c) * 64 + g * 8) = *(const uint4*)tmp;
        }
    }
    __syncthreads();   // A-tile visible; no further barriers until epilogue

    // ---- compute: per chunk per s-step, JIT B frags (L2-hot) + 8 MFMAs ----
    const int nch = c1 + c2 + c3;
    f32x4 acc[4][2] = {};
    for (int kc = 0; kc < nch; ++kc) {
        #pragma unroll
        for (int s = 0; s < 2; ++s) {
            bf16x8 bq[2];
            #pragma unroll
            for (int j = 0; j < 2; ++j) {
                const int col = wc + j * 16 + fr;
                bq[j] = *(const bf16x8*)(WB + (size_t)col * ldw + kc * 64 + s * 32 + fq * 8);
            }
            bf16x8 af[4];
            #pragma unroll
            for (int i = 0; i < 4; ++i)
                af[i] = *(const bf16x8*)(lds + (i * 16 + fr) * AS_LD + kc * 64 + s * 32 + fq * 8);
            #pragma unroll
            for (int j = 0; j < 2; ++j)
                #pragma unroll
                for (int i = 0; i < 4; ++i)
                    acc[i][j] = __builtin_amdgcn_mfma_f32_16x16x32_bf16(bq[j], af[i], acc[i][j], 0, 0, 0);
        }
    }

    // ---- epilogue: 2-pass transpose through LDS, full-line nt stores ----
    // acc[i][j]: C-rows i*16+fr, C-cols wc + j*16 + fq*4 .. +3
    u16* Tb = lds;                          // 32 x TB_LD view
    #pragma unroll
    for (int s2 = 0; s2 < 2; ++s2) {
        __syncthreads();                    // K-loop / previous pass done with lds
        #pragma unroll
        for (int j = 0; j < 2; ++j) {
            const int gc = wc + j * 16 + fq * 4;
            float4 bv = make_float4(0.f, 0.f, 0.f, 0.f);
            if (bias) bv = *(const float4*)&bias[gc];
            #pragma unroll
            for (int ii = 0; ii < 2; ++ii) {
                const int i = s2 * 2 + ii;  // acc row-block
                u16 o[4];
                o[0] = f2bf(fmaxf(acc[i][j][0] + bv.x, 0.f));
                o[1] = f2bf(fmaxf(acc[i][j][1] + bv.y, 0.f));
                o[2] = f2bf(fmaxf(acc[i][j][2] + bv.z, 0.f));
                o[3] = f2bf(fmaxf(acc[i][j][3] + bv.w, 0.f));
                *(uint2*)(Tb + (ii * 16 + fr) * TB_LD + gc) = *(const uint2*)o;
            }
        }
        __syncthreads();                    // half-tile complete
        const int gsl = t & 31;             // 16B granule within 512B row
        const int rb  = t >> 5;             // 0..15
        #pragma unroll
        for (int it2 = 0; it2 < 2; ++it2) {
            const int rl = it2 * 16 + rb;
            const int grr = row0 + s2 * 32 + rl;
            if (grr < M) {
                const u16x8 v = *(const u16x8*)(Tb + rl * TB_LD + gsl * 8);
                __builtin_nontemporal_store(v, (u16x8*)(C + (size_t)grr * 256 + gsl * 8));
            }
        }
    }
}

// WB[n][k] bf16: k<k1 -> src1[n][off1+k]; k1<=k<k1+k2 -> src2[n][off2+k-k1]; else 0
__global__ void build_wb(const float* __restrict__ src1, int lds1, int off1, int k1,
                         const float* __restrict__ src2, int lds2, int off2, int k2,
                         u16* __restrict__ dst, int ldd)
{
    const int n = blockIdx.x;  // 0..255
    for (int k = threadIdx.x; k < ldd; k += blockDim.x) {
        float v = 0.f;
        if (k < k1)           v = src1[(size_t)n * lds1 + off1 + k];
        else if (k < k1 + k2) v = src2[(size_t)n * lds2 + off2 + (k - k1)];
        dst[(size_t)n * ldd + k] = f2bf(v);
    }
}

// FB[e][0:64] = bf16(fbonds[e][0:50]) padded with zeros
__global__ void build_fb(const float* __restrict__ fb, u16* __restrict__ FB, int E)
{
    const int e = blockIdx.x * 4 + (threadIdx.x >> 6);
    if (e >= E) return;
    const int k = threadIdx.x & 63;
    FB[(size_t)e * 64 + k] = (k < 50) ? f2bf(fb[(size_t)e * 50 + k]) : (u16)0;
}

// per-molecule mean over sorted mol_ids; atomh bf16, out fp32
__global__ void segment_mean(const u16* __restrict__ atomh, const int* __restrict__ mol_ids,
                             float* __restrict__ out, int N)
{
    const int m = blockIdx.x;
    const int t = threadIdx.x;
    __shared__ int s_lo, s_hi;
    if (t == 0) {
        int lo = 0, hi = N;
        while (lo < hi) { int mid = (lo + hi) >> 1; if (mol_ids[mid] < m) lo = mid + 1; else hi = mid; }
        s_lo = lo;
        lo = s_lo; hi = N;
        while (lo < hi) { int mid = (lo + hi) >> 1; if (mol_ids[mid] < m + 1) lo = mid + 1; else hi = mid; }
        s_hi = lo;
    }
    __syncthreads();
    const int lo = s_lo, hi = s_hi;
    float sum = 0.f;
    for (int a = lo; a < hi; ++a) sum += bf2f(atomh[(size_t)a * HID + t]);
    const float cnt = (float)((hi - lo) > 1 ? (hi - lo) : 1);
    out[(size_t)m * HID + t] = sum / cnt;
}

extern "C" void kernel_launch(void* const* d_in, const int* in_sizes, int n_in,
                              void* d_out, int out_size, void* d_ws, size_t ws_size,
                              hipStream_t stream)
{
    const float* fatoms = (const float*)d_in[0];
    const float* fbonds = (const float*)d_in[1];
    const int*   agraph = (const int*)d_in[2];
    const int*   bgraph = (const int*)d_in[3];
    const int*   mol_ids = (const int*)d_in[4];
    const float* W_i = (const float*)d_in[7];
    const float* W_h = (const float*)d_in[8];
    const float* W_o = (const float*)d_in[9];
    const float* b_o = (const float*)d_in[10];

    const int N = in_sizes[0] / 39;       // 100000
    const int E = in_sizes[1] / 50;       // 200001
    const int N_MOLS = 1000;
    const int DEPTH = 6;

    const size_t EH = (size_t)E * HID;
    const size_t wbh_sz = (size_t)256 * 320;
    const size_t wbi_sz = (size_t)256 * 64;
    const size_t wbo_sz = (size_t)256 * 320;
    const size_t wsz = wbh_sz + wbi_sz + wbo_sz;
    const size_t fb_sz = (size_t)E * 64;

    const size_t need_nofb = (2 * EH + wsz) * sizeof(u16);
    const size_t need_fb   = (2 * EH + fb_sz + wsz) * sizeof(u16);
    if (ws_size < need_nofb) return;
    const bool use_fb = (ws_size >= need_fb);

    u16* buf0 = (u16*)d_ws;                       // [E][256]
    u16* buf1 = buf0 + EH;                        // [E][256]
    u16* FB   = use_fb ? (buf1 + EH) : nullptr;   // [E][64] bf16 fbonds
    u16* wbh  = (use_fb ? FB + fb_sz : buf1 + EH);
    u16* wbi  = wbh + wbh_sz;
    u16* wbo  = wbi + wbi_sz;

    float* out = (float*)d_out;

    build_wb<<<dim3(256), dim3(64), 0, stream>>>(W_h, 256, 0, 256, W_i, 50, 0, 50, wbh, 320);
    build_wb<<<dim3(256), dim3(64), 0, stream>>>(W_i, 50, 0, 50, W_i, 50, 0, 0, wbi, 64);
    build_wb<<<dim3(256), dim3(64), 0, stream>>>(W_o, 295, 39, 256, W_o, 295, 0, 39, wbo, 320);
    if (use_fb)
        build_fb<<<dim3((E + 3) / 4), dim3(256), 0, stream>>>(fbonds, FB, E);

    const int gE = (E + 63) / 64;     // 3126
    const int gN = (N + 63) / 64;     // 1563

    // layer 0: buf0 = relu(fbonds @ W_i.T)
    if (use_fb)
        fused_layer<<<dim3(gE), dim3(512), 0, stream>>>(
            nullptr, nullptr, 0, FB, 64, 1, nullptr, 0, 0, 0, wbi, 64, nullptr, buf0, E);
    else
        fused_layer<<<dim3(gE), dim3(512), 0, stream>>>(
            nullptr, nullptr, 0, nullptr, 0, 0, fbonds, 50, 50, 1, wbi, 64, nullptr, buf0, E);

    // hidden layers (ping-pong): dst = relu(gather(src)@W_h.T + fbonds@W_i.T)
    u16* src = buf0;
    u16* dst = buf1;
    for (int it = 0; it < DEPTH - 1; ++it) {
        if (use_fb)
            fused_layer<<<dim3(gE), dim3(512), 0, stream>>>(
                src, bgraph, 4, FB, 64, 1, nullptr, 0, 0, 0, wbh, 320, nullptr, dst, E);
        else
            fused_layer<<<dim3(gE), dim3(512), 0, stream>>>(
                src, bgraph, 4, nullptr, 0, 0, fbonds, 50, 50, 1, wbh, 320, nullptr, dst, E);
        u16* tmp = src; src = dst; dst = tmp;
    }
    // after 5 layers: src = buf1 (final message), dst = buf0 (free)

    // output layer: dst = relu(gather_a(src)@W_o[:,39:].T + fatoms@W_o[:,:39].T + b_o)
    fused_layer<<<dim3(gN), dim3(512), 0, stream>>>(
        src, agraph, 4, nullptr, 0, 0, fatoms, 39, 39, 1, wbo, 320, b_o, dst, N);

    // per-molecule mean
    segment_mean<<<dim3(N_MOLS), dim3(256), 0, stream>>>(dst, mol_ids, out, N);
}

// Round 2
// 1099.253 us; speedup vs baseline: 1.1531x; 1.1531x over previous
//
#include <hip/hip_runtime.h>

#define HID 256
#define AS_LD 72    // u16; K-loop A-tile row stride (144 B)
#define TB_LD 264   // u16; epilogue transpose row stride (528 B, 16B-aligned)

typedef unsigned short u16;
typedef unsigned int u32;
typedef short bf16x8 __attribute__((ext_vector_type(8)));
typedef float f32x4 __attribute__((ext_vector_type(4)));
typedef u16 u16x8 __attribute__((ext_vector_type(8)));

static __device__ __forceinline__ float bf2f(u16 b) {
    u32 u = ((u32)b) << 16;
    return __uint_as_float(u);
}
static __device__ __forceinline__ u16 f2bf(float f) {
    u32 u = __float_as_uint(f);
    return (u16)((u + 0x7FFFu + ((u >> 16) & 1u)) >> 16);  // RN-even
}

// ---------------------------------------------------------------------------
// Fused gather + GEMM + relu, tile 64 rows x 256 cols, BK=64, 512 threads.
// Round-0 chunked structure (proven 305 MB fetch: per-chunk temporal
// clustering keeps the active 128-B column slice of Sg L2/L3-resident),
// now SOFTWARE-PIPELINED:
//   - double-buffered LDS A-tile (2 x 64 x AS_LD)
//   - chunk kc+1's gather loads issued into registers BEFORE the barrier
//   - barrier = lgkmcnt(0)-only + raw s_barrier (NOT __syncthreads, whose
//     vmcnt(0) drain would force the prefetch to complete pre-barrier);
//     global prefetch loads stay in flight across barrier + compute (T4)
//   - one barrier per chunk instead of two
// A rows from up to three k-concatenated sources:
//   c1 chunks: sum of 6 rows of Sg via graph (bf16, ld 256, cached loads)
//   c2 chunks: direct rows of Bd            (bf16, nt-loaded)
//   c3 chunks: fp32 rows of Cf (K < Kc)
// B = WB [256 cols][ldw k] bf16, L2-hot, phase-local register loads.
// Epilogue: 2-pass LDS transpose (32x256) -> full-line nontemporal stores.
// ---------------------------------------------------------------------------
__global__ __launch_bounds__(512, 4) void fused_layer(
    const u16* __restrict__ Sg, const int* __restrict__ graph, int c1,
    const u16* __restrict__ Bd, int ldbd, int c2,
    const float* __restrict__ Cf, int ldcf, int Kc, int c3,
    const u16* __restrict__ WB, int ldw,
    const float* __restrict__ bias,
    u16* __restrict__ C, int M)
{
    __shared__ __align__(16) u16 lds[2 * 64 * AS_LD];   // 18,432 B (union: A-dbuf / transpose)

    const int t    = threadIdx.x;
    const int w    = t >> 6;           // 0..7
    const int lane = t & 63;
    const int row0 = blockIdx.x * 64;
    const int wc   = w * 32;           // wave's 32 columns
    const int fr   = lane & 15;
    const int fq   = lane >> 4;

    const int g  = t & 7;              // 16B granule within 128B row-chunk
    const int ra = t >> 3;             // 0..63 -> one row per thread
    const int gr = row0 + ra;
    const int grc = gr < M ? gr : 0;

    int nbi[6];
    const u16* bdp = nullptr;
    if (c1 > 0) {
        const int* gp = graph + (size_t)grc * 6;
        #pragma unroll
        for (int j = 0; j < 6; ++j) nbi[j] = __builtin_nontemporal_load(&gp[j]);
    }
    if (c2 > 0) bdp = Bd + (size_t)grc * ldbd;

    const int nch = c1 + c2 + c3;
    const int nbf = c1 + c2;           // bf16-typed chunks

    // prefetch registers (chunk kc in flight while chunk kc-1 computes)
    u16x8 va[6];
    float fa[8];

    // issue global loads for chunk kc (register destinations, non-blocking)
    auto issue = [&](int kc) {
        if (kc < c1) {
            #pragma unroll
            for (int j = 0; j < 6; ++j)
                va[j] = *(const u16x8*)(Sg + (size_t)nbi[j] * 256 + kc * 64 + g * 8);
        } else if (kc < nbf) {
            va[0] = __builtin_nontemporal_load(
                (const u16x8*)(bdp + (kc - c1) * 64 + g * 8));
        } else {
            const int kb = (kc - nbf) * 64 + g * 8;
            #pragma unroll
            for (int i = 0; i < 8; ++i)
                fa[i] = (gr < M && kb + i < Kc) ? Cf[(size_t)gr * ldcf + kb + i] : 0.f;
        }
    };

    // consume in-flight loads for chunk kc -> bf16 row fragment -> LDS
    auto consume = [&](int kc, u16* Ab) {
        u16 o[8];
        if (kc < c1) {
            float sa[8] = {};
            #pragma unroll
            for (int j = 0; j < 6; ++j)
                #pragma unroll
                for (int e = 0; e < 8; ++e) sa[e] += bf2f(va[j][e]);
            #pragma unroll
            for (int e = 0; e < 8; ++e) o[e] = f2bf(sa[e]);
        } else if (kc < nbf) {
            *(u16x8*)o = va[0];
        } else {
            #pragma unroll
            for (int i = 0; i < 8; ++i) o[i] = f2bf(fa[i]);
        }
        *(uint4*)(Ab + ra * AS_LD + g * 8) = *(const uint4*)o;
    };

    f32x4 acc[4][2] = {};
    issue(0);
    #pragma unroll 1
    for (int kc = 0; kc < nch; ++kc) {
        u16* Ab = lds + (kc & 1) * (64 * AS_LD);
        consume(kc, Ab);                 // waits vmcnt for chunk kc's loads
        if (kc + 1 < nch) issue(kc + 1); // prefetch: in flight across barrier
        // drain LDS writes only; prefetch global loads stay outstanding
        asm volatile("s_waitcnt lgkmcnt(0)" ::: "memory");
        __builtin_amdgcn_s_barrier();
        asm volatile("" ::: "memory");   // fence: no load hoist above barrier

        // ---- compute: per s-step, JIT B frags (L2-hot) then 8 MFMAs ----
        #pragma unroll
        for (int s = 0; s < 2; ++s) {
            bf16x8 bq[2];
            #pragma unroll
            for (int j = 0; j < 2; ++j) {
                const int col = wc + j * 16 + fr;
                bq[j] = *(const bf16x8*)(WB + (size_t)col * ldw + kc * 64 + s * 32 + fq * 8);
            }
            bf16x8 af[4];
            #pragma unroll
            for (int i = 0; i < 4; ++i)
                af[i] = *(const bf16x8*)(Ab + (i * 16 + fr) * AS_LD + s * 32 + fq * 8);
            #pragma unroll
            for (int j = 0; j < 2; ++j)
                #pragma unroll
                for (int i = 0; i < 4; ++i)
                    acc[i][j] = __builtin_amdgcn_mfma_f32_16x16x32_bf16(bq[j], af[i], acc[i][j], 0, 0, 0);
        }
    }

    // ---- epilogue: 2-pass transpose through LDS, full-line nt stores ----
    // acc[i][j]: C-rows i*16+fr, C-cols wc + j*16 + fq*4 .. +3
    u16* Tb = lds;                          // 32 x TB_LD view
    #pragma unroll
    for (int s2 = 0; s2 < 2; ++s2) {
        __syncthreads();                    // K-loop / previous pass done with lds
        #pragma unroll
        for (int j = 0; j < 2; ++j) {
            const int gc = wc + j * 16 + fq * 4;
            float4 bv = make_float4(0.f, 0.f, 0.f, 0.f);
            if (bias) bv = *(const float4*)&bias[gc];
            #pragma unroll
            for (int ii = 0; ii < 2; ++ii) {
                const int i = s2 * 2 + ii;  // acc row-block
                u16 o[4];
                o[0] = f2bf(fmaxf(acc[i][j][0] + bv.x, 0.f));
                o[1] = f2bf(fmaxf(acc[i][j][1] + bv.y, 0.f));
                o[2] = f2bf(fmaxf(acc[i][j][2] + bv.z, 0.f));
                o[3] = f2bf(fmaxf(acc[i][j][3] + bv.w, 0.f));
                *(uint2*)(Tb + (ii * 16 + fr) * TB_LD + gc) = *(const uint2*)o;
            }
        }
        __syncthreads();                    // half-tile complete
        const int gsl = t & 31;             // 16B granule within 512B row
        const int rb  = t >> 5;             // 0..15
        #pragma unroll
        for (int it2 = 0; it2 < 2; ++it2) {
            const int rl = it2 * 16 + rb;
            const int grr = row0 + s2 * 32 + rl;
            if (grr < M) {
                const u16x8 v = *(const u16x8*)(Tb + rl * TB_LD + gsl * 8);
                __builtin_nontemporal_store(v, (u16x8*)(C + (size_t)grr * 256 + gsl * 8));
            }
        }
    }
}

// WB[n][k] bf16: k<k1 -> src1[n][off1+k]; k1<=k<k1+k2 -> src2[n][off2+k-k1]; else 0
__global__ void build_wb(const float* __restrict__ src1, int lds1, int off1, int k1,
                         const float* __restrict__ src2, int lds2, int off2, int k2,
                         u16* __restrict__ dst, int ldd)
{
    const int n = blockIdx.x;  // 0..255
    for (int k = threadIdx.x; k < ldd; k += blockDim.x) {
        float v = 0.f;
        if (k < k1)           v = src1[(size_t)n * lds1 + off1 + k];
        else if (k < k1 + k2) v = src2[(size_t)n * lds2 + off2 + (k - k1)];
        dst[(size_t)n * ldd + k] = f2bf(v);
    }
}

// FB[e][0:64] = bf16(fbonds[e][0:50]) padded with zeros
__global__ void build_fb(const float* __restrict__ fb, u16* __restrict__ FB, int E)
{
    const int e = blockIdx.x * 4 + (threadIdx.x >> 6);
    if (e >= E) return;
    const int k = threadIdx.x & 63;
    FB[(size_t)e * 64 + k] = (k < 50) ? f2bf(fb[(size_t)e * 50 + k]) : (u16)0;
}

// per-molecule mean over sorted mol_ids; atomh bf16, out fp32
__global__ void segment_mean(const u16* __restrict__ atomh, const int* __restrict__ mol_ids,
                             float* __restrict__ out, int N)
{
    const int m = blockIdx.x;
    const int t = threadIdx.x;
    __shared__ int s_lo, s_hi;
    if (t == 0) {
        int lo = 0, hi = N;
        while (lo < hi) { int mid = (lo + hi) >> 1; if (mol_ids[mid] < m) lo = mid + 1; else hi = mid; }
        s_lo = lo;
        lo = s_lo; hi = N;
        while (lo < hi) { int mid = (lo + hi) >> 1; if (mol_ids[mid] < m + 1) lo = mid + 1; else hi = mid; }
        s_hi = lo;
    }
    __syncthreads();
    const int lo = s_lo, hi = s_hi;
    float sum = 0.f;
    for (int a = lo; a < hi; ++a) sum += bf2f(atomh[(size_t)a * HID + t]);
    const float cnt = (float)((hi - lo) > 1 ? (hi - lo) : 1);
    out[(size_t)m * HID + t] = sum / cnt;
}

extern "C" void kernel_launch(void* const* d_in, const int* in_sizes, int n_in,
                              void* d_out, int out_size, void* d_ws, size_t ws_size,
                              hipStream_t stream)
{
    const float* fatoms = (const float*)d_in[0];
    const float* fbonds = (const float*)d_in[1];
    const int*   agraph = (const int*)d_in[2];
    const int*   bgraph = (const int*)d_in[3];
    const int*   mol_ids = (const int*)d_in[4];
    const float* W_i = (const float*)d_in[7];
    const float* W_h = (const float*)d_in[8];
    const float* W_o = (const float*)d_in[9];
    const float* b_o = (const float*)d_in[10];

    const int N = in_sizes[0] / 39;       // 100000
    const int E = in_sizes[1] / 50;       // 200001
    const int N_MOLS = 1000;
    const int DEPTH = 6;

    const size_t EH = (size_t)E * HID;
    const size_t wbh_sz = (size_t)256 * 320;
    const size_t wbi_sz = (size_t)256 * 64;
    const size_t wbo_sz = (size_t)256 * 320;
    const size_t wsz = wbh_sz + wbi_sz + wbo_sz;
    const size_t fb_sz = (size_t)E * 64;

    const size_t need_nofb = (2 * EH + wsz) * sizeof(u16);
    const size_t need_fb   = (2 * EH + fb_sz + wsz) * sizeof(u16);
    if (ws_size < need_nofb) return;
    const bool use_fb = (ws_size >= need_fb);

    u16* buf0 = (u16*)d_ws;                       // [E][256]
    u16* buf1 = buf0 + EH;                        // [E][256]
    u16* FB   = use_fb ? (buf1 + EH) : nullptr;   // [E][64] bf16 fbonds
    u16* wbh  = (use_fb ? FB + fb_sz : buf1 + EH);
    u16* wbi  = wbh + wbh_sz;
    u16* wbo  = wbi + wbi_sz;

    float* out = (float*)d_out;

    build_wb<<<dim3(256), dim3(64), 0, stream>>>(W_h, 256, 0, 256, W_i, 50, 0, 50, wbh, 320);
    build_wb<<<dim3(256), dim3(64), 0, stream>>>(W_i, 50, 0, 50, W_i, 50, 0, 0, wbi, 64);
    build_wb<<<dim3(256), dim3(64), 0, stream>>>(W_o, 295, 39, 256, W_o, 295, 0, 39, wbo, 320);
    if (use_fb)
        build_fb<<<dim3((E + 3) / 4), dim3(256), 0, stream>>>(fbonds, FB, E);

    const int gE = (E + 63) / 64;     // 3126
    const int gN = (N + 63) / 64;     // 1563

    // layer 0: buf0 = relu(fbonds @ W_i.T)
    if (use_fb)
        fused_layer<<<dim3(gE), dim3(512), 0, stream>>>(
            nullptr, nullptr, 0, FB, 64, 1, nullptr, 0, 0, 0, wbi, 64, nullptr, buf0, E);
    else
        fused_layer<<<dim3(gE), dim3(512), 0, stream>>>(
            nullptr, nullptr, 0, nullptr, 0, 0, fbonds, 50, 50, 1, wbi, 64, nullptr, buf0, E);

    // hidden layers (ping-pong): dst = relu(gather(src)@W_h.T + fbonds@W_i.T)
    u16* src = buf0;
    u16* dst = buf1;
    for (int it = 0; it < DEPTH - 1; ++it) {
        if (use_fb)
            fused_layer<<<dim3(gE), dim3(512), 0, stream>>>(
                src, bgraph, 4, FB, 64, 1, nullptr, 0, 0, 0, wbh, 320, nullptr, dst, E);
        else
            fused_layer<<<dim3(gE), dim3(512), 0, stream>>>(
                src, bgraph, 4, nullptr, 0, 0, fbonds, 50, 50, 1, wbh, 320, nullptr, dst, E);
        u16* tmp = src; src = dst; dst = tmp;
    }
    // after 5 layers: src = buf1 (final message), dst = buf0 (free)

    // output layer: dst = relu(gather_a(src)@W_o[:,39:].T + fatoms@W_o[:,:39].T + b_o)
    fused_layer<<<dim3(gN), dim3(512), 0, stream>>>(
        src, agraph, 4, nullptr, 0, 0, fatoms, 39, 39, 1, wbo, 320, b_o, dst, N);

    // per-molecule mean
    segment_mean<<<dim3(N_MOLS), dim3(256), 0, stream>>>(dst, mol_ids, out, N);
}

// Round 3
// 976.405 us; speedup vs baseline: 1.2982x; 1.1258x over previous
//
#include <hip/hip_runtime.h>

#define HID 256
#define AS_LD 72    // u16; K-loop A-tile row stride (144 B)
#define TB_LD 264   // u16; epilogue transpose row stride (528 B, 16B-aligned)

typedef unsigned short u16;
typedef unsigned int u32;
typedef short bf16x8 __attribute__((ext_vector_type(8)));
typedef float f32x4 __attribute__((ext_vector_type(4)));
typedef u16 u16x8 __attribute__((ext_vector_type(8)));

static __device__ __forceinline__ float bf2f(u16 b) {
    u32 u = ((u32)b) << 16;
    return __uint_as_float(u);
}
static __device__ __forceinline__ u16 f2bf(float f) {
    u32 u = __float_as_uint(f);
    return (u16)((u + 0x7FFFu + ((u >> 16) & 1u)) >> 16);  // RN-even
}

// ---------------------------------------------------------------------------
// Fused gather + GEMM + relu, tile 64 rows x 256 cols, BK=64, 512 threads.
// Chunked staging (proven 305 MB fetch: per-chunk temporal clustering keeps
// the active 128-B column slice of Sg cache-resident), software-pipelined
// with ISSUE-ORDER DISCIPLINE so counted vmcnt waits are legal:
//   per chunk kc:
//     1. bq loads (WB B-frags, L2-hot)     <- oldest of this iteration
//     2. consume(kc): wait vmcnt(4) for gather kc (bq still in flight),
//        fp32 sum -> bf16 -> LDS (double-buffered A-tile)
//     3. issue(kc+1): 6 gather loads        <- youngest; stay in flight
//     4. s_waitcnt lgkmcnt(0) + raw s_barrier (no vmcnt drain)
//     5. compute: ds_read af + 16 MFMAs; bq needs only vmcnt(6) ->
//        the kc+1 gathers remain outstanding across barrier + compute
// (Round-2 lesson: bq issued AFTER the prefetch forces vmcnt(0) in compute,
//  serializing gather latency onto the critical path.)
// A rows from up to three k-concatenated sources:
//   c1 chunks: sum of 6 rows of Sg via graph (bf16, ld 256)
//   c2 chunks: direct rows of Bd            (bf16, nt-loaded)
//   c3 chunks: fp32 rows of Cf (K < Kc)
// Epilogue: 2-pass LDS transpose (32x256) -> full-line nontemporal stores.
// ---------------------------------------------------------------------------
__global__ __launch_bounds__(512, 4) void fused_layer(
    const u16* __restrict__ Sg, const int* __restrict__ graph, int c1,
    const u16* __restrict__ Bd, int ldbd, int c2,
    const float* __restrict__ Cf, int ldcf, int Kc, int c3,
    const u16* __restrict__ WB, int ldw,
    const float* __restrict__ bias,
    u16* __restrict__ C, int M)
{
    __shared__ __align__(16) u16 lds[2 * 64 * AS_LD];   // 18,432 B (union: A-dbuf / transpose)

    const int t    = threadIdx.x;
    const int w    = t >> 6;           // 0..7
    const int lane = t & 63;
    const int row0 = blockIdx.x * 64;
    const int wc   = w * 32;           // wave's 32 columns
    const int fr   = lane & 15;
    const int fq   = lane >> 4;

    const int g  = t & 7;              // 16B granule within 128B row-chunk
    const int ra = t >> 3;             // 0..63 -> one row per thread
    const int gr = row0 + ra;
    const int grc = gr < M ? gr : 0;

    int nbi[6];
    const u16* bdp = nullptr;
    if (c1 > 0) {
        const int* gp = graph + (size_t)grc * 6;
        #pragma unroll
        for (int j = 0; j < 6; ++j) nbi[j] = __builtin_nontemporal_load(&gp[j]);
    }
    if (c2 > 0) bdp = Bd + (size_t)grc * ldbd;

    const int nch = c1 + c2 + c3;
    const int nbf = c1 + c2;           // bf16-typed chunks

    // prefetch registers (chunk kc in flight while chunk kc-1 computes)
    u16x8 va[6];
    float fa[8];

    // issue global loads for chunk kc (register destinations, non-blocking)
    auto issue = [&](int kc) {
        if (kc < c1) {
            #pragma unroll
            for (int j = 0; j < 6; ++j)
                va[j] = *(const u16x8*)(Sg + (size_t)nbi[j] * 256 + kc * 64 + g * 8);
        } else if (kc < nbf) {
            va[0] = __builtin_nontemporal_load(
                (const u16x8*)(bdp + (kc - c1) * 64 + g * 8));
        } else {
            const int kb = (kc - nbf) * 64 + g * 8;
            #pragma unroll
            for (int i = 0; i < 8; ++i)
                fa[i] = (gr < M && kb + i < Kc) ? Cf[(size_t)gr * ldcf + kb + i] : 0.f;
        }
    };

    // consume in-flight loads for chunk kc -> bf16 row fragment -> LDS
    auto consume = [&](int kc, u16* Ab) {
        u16 o[8];
        if (kc < c1) {
            float sa[8] = {};
            #pragma unroll
            for (int j = 0; j < 6; ++j)
                #pragma unroll
                for (int e = 0; e < 8; ++e) sa[e] += bf2f(va[j][e]);
            #pragma unroll
            for (int e = 0; e < 8; ++e) o[e] = f2bf(sa[e]);
        } else if (kc < nbf) {
            *(u16x8*)o = va[0];
        } else {
            #pragma unroll
            for (int i = 0; i < 8; ++i) o[i] = f2bf(fa[i]);
        }
        *(uint4*)(Ab + ra * AS_LD + g * 8) = *(const uint4*)o;
    };

    f32x4 acc[4][2] = {};
    issue(0);
    #pragma unroll 1
    for (int kc = 0; kc < nch; ++kc) {
        u16* Ab = lds + (kc & 1) * (64 * AS_LD);

        // 1. B fragments for this chunk FIRST (older than the prefetch, so
        //    the compute phase needs only a counted vmcnt wait for them)
        bf16x8 bq[2][2];
        #pragma unroll
        for (int s = 0; s < 2; ++s)
            #pragma unroll
            for (int j = 0; j < 2; ++j) {
                const int col = wc + j * 16 + fr;
                bq[s][j] = *(const bf16x8*)(WB + (size_t)col * ldw + kc * 64 + s * 32 + fq * 8);
            }

        // 2. consume chunk kc (waits for its gathers; bq still in flight)
        consume(kc, Ab);

        // 3. prefetch chunk kc+1 (youngest; stays outstanding across
        //    barrier + compute + next iteration's bq/consume)
        if (kc + 1 < nch) issue(kc + 1);

        // 4. drain LDS writes only; global prefetch stays outstanding
        asm volatile("s_waitcnt lgkmcnt(0)" ::: "memory");
        __builtin_amdgcn_s_barrier();
        asm volatile("" ::: "memory");   // fence: no memory-op hoist above barrier

        // 5. compute: ds_read A frags + 16 MFMAs (bq wait = vmcnt(6))
        #pragma unroll
        for (int s = 0; s < 2; ++s) {
            bf16x8 af[4];
            #pragma unroll
            for (int i = 0; i < 4; ++i)
                af[i] = *(const bf16x8*)(Ab + (i * 16 + fr) * AS_LD + s * 32 + fq * 8);
            #pragma unroll
            for (int j = 0; j < 2; ++j)
                #pragma unroll
                for (int i = 0; i < 4; ++i)
                    acc[i][j] = __builtin_amdgcn_mfma_f32_16x16x32_bf16(bq[s][j], af[i], acc[i][j], 0, 0, 0);
        }
    }

    // ---- epilogue: 2-pass transpose through LDS, full-line nt stores ----
    // acc[i][j]: C-rows i*16+fr, C-cols wc + j*16 + fq*4 .. +3
    u16* Tb = lds;                          // 32 x TB_LD view
    #pragma unroll
    for (int s2 = 0; s2 < 2; ++s2) {
        __syncthreads();                    // K-loop / previous pass done with lds
        #pragma unroll
        for (int j = 0; j < 2; ++j) {
            const int gc = wc + j * 16 + fq * 4;
            float4 bv = make_float4(0.f, 0.f, 0.f, 0.f);
            if (bias) bv = *(const float4*)&bias[gc];
            #pragma unroll
            for (int ii = 0; ii < 2; ++ii) {
                const int i = s2 * 2 + ii;  // acc row-block
                u16 o[4];
                o[0] = f2bf(fmaxf(acc[i][j][0] + bv.x, 0.f));
                o[1] = f2bf(fmaxf(acc[i][j][1] + bv.y, 0.f));
                o[2] = f2bf(fmaxf(acc[i][j][2] + bv.z, 0.f));
                o[3] = f2bf(fmaxf(acc[i][j][3] + bv.w, 0.f));
                *(uint2*)(Tb + (ii * 16 + fr) * TB_LD + gc) = *(const uint2*)o;
            }
        }
        __syncthreads();                    // half-tile complete
        const int gsl = t & 31;             // 16B granule within 512B row
        const int rb  = t >> 5;             // 0..15
        #pragma unroll
        for (int it2 = 0; it2 < 2; ++it2) {
            const int rl = it2 * 16 + rb;
            const int grr = row0 + s2 * 32 + rl;
            if (grr < M) {
                const u16x8 v = *(const u16x8*)(Tb + rl * TB_LD + gsl * 8);
                __builtin_nontemporal_store(v, (u16x8*)(C + (size_t)grr * 256 + gsl * 8));
            }
        }
    }
}

// WB[n][k] bf16: k<k1 -> src1[n][off1+k]; k1<=k<k1+k2 -> src2[n][off2+k-k1]; else 0
__global__ void build_wb(const float* __restrict__ src1, int lds1, int off1, int k1,
                         const float* __restrict__ src2, int lds2, int off2, int k2,
                         u16* __restrict__ dst, int ldd)
{
    const int n = blockIdx.x;  // 0..255
    for (int k = threadIdx.x; k < ldd; k += blockDim.x) {
        float v = 0.f;
        if (k < k1)           v = src1[(size_t)n * lds1 + off1 + k];
        else if (k < k1 + k2) v = src2[(size_t)n * lds2 + off2 + (k - k1)];
        dst[(size_t)n * ldd + k] = f2bf(v);
    }
}

// FB[e][0:64] = bf16(fbonds[e][0:50]) padded with zeros
__global__ void build_fb(const float* __restrict__ fb, u16* __restrict__ FB, int E)
{
    const int e = blockIdx.x * 4 + (threadIdx.x >> 6);
    if (e >= E) return;
    const int k = threadIdx.x & 63;
    FB[(size_t)e * 64 + k] = (k < 50) ? f2bf(fb[(size_t)e * 50 + k]) : (u16)0;
}

// per-molecule mean over sorted mol_ids; atomh bf16, out fp32
__global__ void segment_mean(const u16* __restrict__ atomh, const int* __restrict__ mol_ids,
                             float* __restrict__ out, int N)
{
    const int m = blockIdx.x;
    const int t = threadIdx.x;
    __shared__ int s_lo, s_hi;
    if (t == 0) {
        int lo = 0, hi = N;
        while (lo < hi) { int mid = (lo + hi) >> 1; if (mol_ids[mid] < m) lo = mid + 1; else hi = mid; }
        s_lo = lo;
        lo = s_lo; hi = N;
        while (lo < hi) { int mid = (lo + hi) >> 1; if (mol_ids[mid] < m + 1) lo = mid + 1; else hi = mid; }
        s_hi = lo;
    }
    __syncthreads();
    const int lo = s_lo, hi = s_hi;
    float sum = 0.f;
    for (int a = lo; a < hi; ++a) sum += bf2f(atomh[(size_t)a * HID + t]);
    const float cnt = (float)((hi - lo) > 1 ? (hi - lo) : 1);
    out[(size_t)m * HID + t] = sum / cnt;
}

extern "C" void kernel_launch(void* const* d_in, const int* in_sizes, int n_in,
                              void* d_out, int out_size, void* d_ws, size_t ws_size,
                              hipStream_t stream)
{
    const float* fatoms = (const float*)d_in[0];
    const float* fbonds = (const float*)d_in[1];
    const int*   agraph = (const int*)d_in[2];
    const int*   bgraph = (const int*)d_in[3];
    const int*   mol_ids = (const int*)d_in[4];
    const float* W_i = (const float*)d_in[7];
    const float* W_h = (const float*)d_in[8];
    const float* W_o = (const float*)d_in[9];
    const float* b_o = (const float*)d_in[10];

    const int N = in_sizes[0] / 39;       // 100000
    const int E = in_sizes[1] / 50;       // 200001
    const int N_MOLS = 1000;
    const int DEPTH = 6;

    const size_t EH = (size_t)E * HID;
    const size_t wbh_sz = (size_t)256 * 320;
    const size_t wbi_sz = (size_t)256 * 64;
    const size_t wbo_sz = (size_t)256 * 320;
    const size_t wsz = wbh_sz + wbi_sz + wbo_sz;
    const size_t fb_sz = (size_t)E * 64;

    const size_t need_nofb = (2 * EH + wsz) * sizeof(u16);
    const size_t need_fb   = (2 * EH + fb_sz + wsz) * sizeof(u16);
    if (ws_size < need_nofb) return;
    const bool use_fb = (ws_size >= need_fb);

    u16* buf0 = (u16*)d_ws;                       // [E][256]
    u16* buf1 = buf0 + EH;                        // [E][256]
    u16* FB   = use_fb ? (buf1 + EH) : nullptr;   // [E][64] bf16 fbonds
    u16* wbh  = (use_fb ? FB + fb_sz : buf1 + EH);
    u16* wbi  = wbh + wbh_sz;
    u16* wbo  = wbi + wbi_sz;

    float* out = (float*)d_out;

    build_wb<<<dim3(256), dim3(64), 0, stream>>>(W_h, 256, 0, 256, W_i, 50, 0, 50, wbh, 320);
    build_wb<<<dim3(256), dim3(64), 0, stream>>>(W_i, 50, 0, 50, W_i, 50, 0, 0, wbi, 64);
    build_wb<<<dim3(256), dim3(64), 0, stream>>>(W_o, 295, 39, 256, W_o, 295, 0, 39, wbo, 320);
    if (use_fb)
        build_fb<<<dim3((E + 3) / 4), dim3(256), 0, stream>>>(fbonds, FB, E);

    const int gE = (E + 63) / 64;     // 3126
    const int gN = (N + 63) / 64;     // 1563

    // layer 0: buf0 = relu(fbonds @ W_i.T)
    if (use_fb)
        fused_layer<<<dim3(gE), dim3(512), 0, stream>>>(
            nullptr, nullptr, 0, FB, 64, 1, nullptr, 0, 0, 0, wbi, 64, nullptr, buf0, E);
    else
        fused_layer<<<dim3(gE), dim3(512), 0, stream>>>(
            nullptr, nullptr, 0, nullptr, 0, 0, fbonds, 50, 50, 1, wbi, 64, nullptr, buf0, E);

    // hidden layers (ping-pong): dst = relu(gather(src)@W_h.T + fbonds@W_i.T)
    u16* src = buf0;
    u16* dst = buf1;
    for (int it = 0; it < DEPTH - 1; ++it) {
        if (use_fb)
            fused_layer<<<dim3(gE), dim3(512), 0, stream>>>(
                src, bgraph, 4, FB, 64, 1, nullptr, 0, 0, 0, wbh, 320, nullptr, dst, E);
        else
            fused_layer<<<dim3(gE), dim3(512), 0, stream>>>(
                src, bgraph, 4, nullptr, 0, 0, fbonds, 50, 50, 1, wbh, 320, nullptr, dst, E);
        u16* tmp = src; src = dst; dst = tmp;
    }
    // after 5 layers: src = buf1 (final message), dst = buf0 (free)

    // output layer: dst = relu(gather_a(src)@W_o[:,39:].T + fatoms@W_o[:,:39].T + b_o)
    fused_layer<<<dim3(gN), dim3(512), 0, stream>>>(
        src, agraph, 4, nullptr, 0, 0, fatoms, 39, 39, 1, wbo, 320, b_o, dst, N);

    // per-molecule mean
    segment_mean<<<dim3(N_MOLS), dim3(256), 0, stream>>>(dst, mol_ids, out, N);
}